// Round 1
// baseline (746.620 us; speedup 1.0000x reference)
//
#include <hip/hip_runtime.h>
#include <hip/hip_bf16.h>

// TreeLSTM on MI355X: one persistent workgroup per tree (256 trees == 256 CUs).
// Phase 1: leaves  x = relu(feats@W1^T+b1); iou = x@W_iou^T; apply_node(c_in=0)
// Phase 2: 9 levels toward root: f-gates GEMM -> c_red; iou GEMM -> apply_node
// Final:   out = c_root @ W_out^T + b_out  (computed in-kernel, lanes 0..31)
//
// Weights live in LDS as bf16, XOR-swizzled (row-stride-256B bank-conflict fix).
// h mailboxes: bf16 in ws. c mailboxes: f32 in ws (bf16 fallback if ws small).
// c_red scratch overlays the internal-node rows of feats (never read by ref;
// harness restores d_in before every launch).

typedef __bf16 bf16x8 __attribute__((ext_vector_type(8)));
typedef float  f32x4  __attribute__((ext_vector_type(4)));
typedef unsigned int u32x4 __attribute__((ext_vector_type(4)));

#define MFMA16(a,b,c) __builtin_amdgcn_mfma_f32_16x16x32_bf16((a),(b),(c),0,0,0)

__device__ __forceinline__ float fast_sigmoid(float x){
    return __builtin_amdgcn_rcpf(1.0f + __expf(-x));   // exp(inf)->inf, rcp(inf)->0: safe
}
__device__ __forceinline__ float fast_tanh(float x){
    float ax = fabsf(x);
    float e  = __expf(-2.0f*ax);                        // in (0,1]: no overflow
    float t  = (1.0f - e) * __builtin_amdgcn_rcpf(1.0f + e);
    return x < 0.0f ? -t : t;
}
__device__ __forceinline__ unsigned pack2bf(float a, float b){
    unsigned short ua = __builtin_bit_cast(unsigned short, (__bf16)a);
    unsigned short ub = __builtin_bit_cast(unsigned short, (__bf16)b);
    return (unsigned)ua | ((unsigned)ub << 16);
}
// swizzled byte offset inside a [rows][128] bf16 LDS tile (row stride 256B)
__device__ __forceinline__ int swzoff(int row, int kByte){
    return row*256 + (kByte ^ ((row & 7) << 4));
}
// B/A fragment read: row = rowBase+(lane&15), k-elems = 32*ks + 8*(lane>>4) .. +7
__device__ __forceinline__ bf16x8 lds_frag(const char* base, int rowBase, int lane, int ks){
    int row = rowBase + (lane & 15);
    int kB  = ks*64 + ((lane >> 4) << 4);
    return *(const bf16x8*)(base + swzoff(row, kB));
}
// f32 [rows][128] global -> bf16 swizzled LDS
__device__ __forceinline__ void load_w_lds(char* dst, const float* __restrict__ src,
                                           int rows, int tid){
    int total = rows * 32;                      // 4-float quads
    for (int t = tid; t < total; t += 512){
        int row = t >> 5;
        int kq  = (t & 31) << 2;                // element index, multiple of 4
        f32x4 v = *(const f32x4*)(src + row*128 + kq);
        unsigned lo = pack2bf(v[0], v[1]);
        unsigned hi = pack2bf(v[2], v[3]);
        unsigned long long val = (unsigned long long)lo | ((unsigned long long)hi << 32);
        *(unsigned long long*)(dst + swzoff(row, kq*2)) = val;
    }
}

template<typename CT>
__global__ __launch_bounds__(512, 2)
void treelstm_kernel(const float* __restrict__ feats,
                     const float* __restrict__ W1,   const float* __restrict__ b1,
                     const float* __restrict__ Wiou, const float* __restrict__ Uiou,
                     const float* __restrict__ biou, const float* __restrict__ Uf,
                     const float* __restrict__ bfv_, const float* __restrict__ Wout,
                     const float* __restrict__ bout,
                     float* __restrict__ out,
                     __bf16* __restrict__ h0g, __bf16* __restrict__ h1g,
                     CT* __restrict__ c0g, CT* __restrict__ c1g,
                     float* __restrict__ credg)
{
    extern __shared__ char smem[];
    const int tid  = threadIdx.x;
    const int lane = tid & 63;
    const int wave = tid >> 6;
    const int q    = lane >> 4;
    const int r    = lane & 15;
    const int tree = blockIdx.x;

    load_w_lds(smem,         W1,   128, tid);
    load_w_lds(smem + 32768, Wiou, 384, tid);
    __syncthreads();

    const float* featsLeaf = feats + ((size_t)tree*1023 + 511)*128;
    __bf16* h0t = h0g + (size_t)tree*512*128;
    CT*     c0t = c0g + (size_t)tree*512*128;
    __bf16* h1t = h1g + (size_t)tree*256*128;
    CT*     c1t = c1g + (size_t)tree*256*128;
    float*  credt = credg + (size_t)tree*(1023*128);   // rows 0..255 used (< leaf rows)

    // ---------------- Phase 1: leaves ----------------
    // GEMM1 computes x^T = W1 * feats^T so feats loads are contiguous per lane;
    // shuffle-transpose converts x^T D-frags into A-frags for GEMM2 (no LDS).
    for (int chunk = wave; chunk < 32; chunk += 8){
        bf16x8 bfeat[4];
        #pragma unroll
        for (int ks = 0; ks < 4; ++ks){
            const float* p = featsLeaf + (size_t)(chunk*16 + r)*128 + ks*32 + q*8;
            f32x4 lo = *(const f32x4*)p;
            f32x4 hi = *(const f32x4*)(p+4);
            bf16x8 t;
            t[0]=(__bf16)lo[0]; t[1]=(__bf16)lo[1]; t[2]=(__bf16)lo[2]; t[3]=(__bf16)lo[3];
            t[4]=(__bf16)hi[0]; t[5]=(__bf16)hi[1]; t[6]=(__bf16)hi[2]; t[7]=(__bf16)hi[3];
            bfeat[ks] = t;
        }
        f32x4 zero4 = {0.f,0.f,0.f,0.f};
        f32x4 acc1[8];
        #pragma unroll
        for (int hb=0;hb<8;++hb) acc1[hb] = zero4;
        #pragma unroll
        for (int ks=0;ks<4;++ks){
            #pragma unroll
            for (int hb=0;hb<8;++hb){
                bf16x8 a1 = lds_frag(smem, hb*16, lane, ks);
                acc1[hb] = MFMA16(a1, bfeat[ks], acc1[hb]);
            }
        }
        // relu + bias, pack to bf16 pairs (lane holds x[r][16*hb+4*q+m], m=0..3)
        unsigned p01[8], p23[8];
        #pragma unroll
        for (int hb=0;hb<8;++hb){
            int hbase = hb*16 + q*4;
            float x0 = fmaxf(acc1[hb][0] + b1[hbase+0], 0.f);
            float x1 = fmaxf(acc1[hb][1] + b1[hbase+1], 0.f);
            float x2 = fmaxf(acc1[hb][2] + b1[hbase+2], 0.f);
            float x3 = fmaxf(acc1[hb][3] + b1[hbase+3], 0.f);
            p01[hb] = pack2bf(x0,x1);
            p23[hb] = pack2bf(x2,x3);
        }
        f32x4 acc2[24];
        #pragma unroll
        for (int i2=0;i2<24;++i2) acc2[i2] = zero4;
        const char* wiouL = smem + 32768;
        const int srcA = ((2*q)&3)*16 + r;        // j=0..3 source lane
        const int srcB = ((2*q+1)&3)*16 + r;      // j=4..7 source lane
        const bool hiH = (q >= 2);                // hb' = 2*ks + (q>>1)
        #pragma unroll
        for (int ks=0;ks<4;++ks){
            unsigned t0a = (unsigned)__shfl((int)p01[2*ks],   srcA, 64);
            unsigned t0b = (unsigned)__shfl((int)p01[2*ks+1], srcA, 64);
            unsigned t1a = (unsigned)__shfl((int)p23[2*ks],   srcA, 64);
            unsigned t1b = (unsigned)__shfl((int)p23[2*ks+1], srcA, 64);
            unsigned t2a = (unsigned)__shfl((int)p01[2*ks],   srcB, 64);
            unsigned t2b = (unsigned)__shfl((int)p01[2*ks+1], srcB, 64);
            unsigned t3a = (unsigned)__shfl((int)p23[2*ks],   srcB, 64);
            unsigned t3b = (unsigned)__shfl((int)p23[2*ks+1], srcB, 64);
            u32x4 tv;
            tv[0] = hiH ? t0b : t0a;
            tv[1] = hiH ? t1b : t1a;
            tv[2] = hiH ? t2b : t2a;
            tv[3] = hiH ? t3b : t3a;
            bf16x8 a2 = __builtin_bit_cast(bf16x8, tv);
            #pragma unroll
            for (int nbt=0;nbt<24;++nbt){
                bf16x8 b2 = lds_frag(wiouL, nbt*16, lane, ks);
                acc2[nbt] = MFMA16(a2, b2, acc2[nbt]);
            }
        }
        // apply_node with c_in = 0
        #pragma unroll
        for (int cb=0;cb<8;++cb){
            int col = cb*16 + r;
            float bi = biou[col], bo = biou[col+128], bu = biou[col+256];
            #pragma unroll
            for (int m=0;m<4;++m){
                int lr = chunk*16 + q*4 + m;
                float cv = fast_sigmoid(acc2[cb][m]+bi)   * fast_tanh(acc2[cb+16][m]+bu);
                float hv = fast_sigmoid(acc2[cb+8][m]+bo) * fast_tanh(cv);
                h0t[lr*128 + col] = (__bf16)hv;
                c0t[lr*128 + col] = (CT)cv;
            }
        }
    }
    __syncthreads();
    load_w_lds(smem,         Uf,   128, tid);
    load_w_lds(smem + 32768, Uiou, 384, tid);
    __syncthreads();

    // ---------------- Phase 2: levels 8..0 ----------------
    __bf16* hPrev = h0t; CT* cPrev = c0t;
    __bf16* hCur  = h1t; CT* cCur  = c1t;

    #pragma unroll 1
    for (int lvl = 8; lvl >= 0; --lvl){
        const int n = 1 << lvl;
        // ---- F step: fpre = hPrev @ Uf^T + bf; c_red[node] = sum_child sig(fpre)*cPrev
        const int fchunks = (2*n + 15) >> 4;
        for (int chunk = wave; chunk < fchunks; chunk += 8){
            bf16x8 af[4];
            #pragma unroll
            for (int ks=0;ks<4;++ks)
                af[ks] = *(const bf16x8*)(hPrev + (chunk*16 + r)*128 + ks*32 + q*8);
            f32x4 zero4 = {0.f,0.f,0.f,0.f};
            f32x4 acc[8];
            #pragma unroll
            for (int nb=0;nb<8;++nb) acc[nb] = zero4;
            #pragma unroll
            for (int ks=0;ks<4;++ks){
                #pragma unroll
                for (int nb=0;nb<8;++nb)
                    acc[nb] = MFMA16(af[ks], lds_frag(smem, nb*16, lane, ks), acc[nb]);
            }
            #pragma unroll
            for (int nb=0;nb<8;++nb){
                int col = nb*16 + r;
                float bfv = bfv_[col];
                int crow = chunk*16 + q*4;
                float fc0 = fast_sigmoid(acc[nb][0]+bfv) * (float)cPrev[(crow+0)*128 + col];
                float fc1 = fast_sigmoid(acc[nb][1]+bfv) * (float)cPrev[(crow+1)*128 + col];
                float fc2 = fast_sigmoid(acc[nb][2]+bfv) * (float)cPrev[(crow+2)*128 + col];
                float fc3 = fast_sigmoid(acc[nb][3]+bfv) * (float)cPrev[(crow+3)*128 + col];
                int node0 = chunk*8 + q*2;                 // lane rows pair in-lane
                if (node0   < n) credt[node0*128 + col]     = fc0 + fc1;
                if (node0+1 < n) credt[(node0+1)*128 + col] = fc2 + fc3;
            }
        }
        __syncthreads();
        // ---- IOU step: iou = (h2j + h2j+1) @ Uiou^T; apply_node with c_red
        const int iunits = ((n + 15) >> 4) << 3;
        const char* uiouL = smem + 32768;
        for (int u = wave; u < iunits; u += 8){
            const int chunk = u >> 3, cb = u & 7;
            bf16x8 ac[4];
            #pragma unroll
            for (int ks=0;ks<4;++ks){
                int rr = chunk*16 + r;
                bf16x8 ha  = *(const bf16x8*)(hPrev + (size_t)(2*rr)*128   + ks*32 + q*8);
                bf16x8 hb2 = *(const bf16x8*)(hPrev + (size_t)(2*rr+1)*128 + ks*32 + q*8);
                bf16x8 t;
                #pragma unroll
                for (int e=0;e<8;++e) t[e] = (__bf16)((float)ha[e] + (float)hb2[e]);
                ac[ks] = t;
            }
            f32x4 ai = {0.f,0.f,0.f,0.f}, ao = ai, au = ai;
            #pragma unroll
            for (int ks=0;ks<4;++ks){
                ai = MFMA16(ac[ks], lds_frag(uiouL, cb*16,       lane, ks), ai);
                ao = MFMA16(ac[ks], lds_frag(uiouL, 128 + cb*16, lane, ks), ao);
                au = MFMA16(ac[ks], lds_frag(uiouL, 256 + cb*16, lane, ks), au);
            }
            int col = cb*16 + r;
            float bi = biou[col], bo = biou[col+128], bu = biou[col+256];
            #pragma unroll
            for (int m=0;m<4;++m){
                int rr = chunk*16 + q*4 + m;
                if (rr < n){
                    float cv = fast_sigmoid(ai[m]+bi)*fast_tanh(au[m]+bu) + credt[rr*128 + col];
                    float hv = fast_sigmoid(ao[m]+bo)*fast_tanh(cv);
                    hCur[rr*128 + col] = (__bf16)hv;
                    cCur[rr*128 + col] = (CT)cv;
                }
            }
        }
        __syncthreads();
        { __bf16* th=hPrev; hPrev=hCur; hCur=th; CT* tc=cPrev; cPrev=cCur; cCur=tc; }
    }

    // ---------------- Final: out = c_root @ Wout^T + bout ----------------
    if (tid < 32){
        float acc = bout[tid];
        #pragma unroll 8
        for (int k=0;k<128;++k)
            acc += (float)cPrev[k] * Wout[tid*128 + k];
        out[tree*32 + tid] = acc;
    }
}

extern "C" void kernel_launch(void* const* d_in, const int* in_sizes, int n_in,
                              void* d_out, int out_size, void* d_ws, size_t ws_size,
                              hipStream_t stream)
{
    (void)in_sizes; (void)n_in; (void)out_size;
    const float* feats = (const float*)d_in[0];
    const float* W1    = (const float*)d_in[2];
    const float* b1    = (const float*)d_in[3];
    const float* Wiou  = (const float*)d_in[4];
    const float* Uiou  = (const float*)d_in[5];
    const float* biou  = (const float*)d_in[6];
    const float* Uf    = (const float*)d_in[7];
    const float* bf    = (const float*)d_in[8];
    const float* Wout  = (const float*)d_in[9];
    const float* bout  = (const float*)d_in[10];
    float* out  = (float*)d_out;
    float* cred = (float*)d_in[0];   // overlay: internal-node feats rows never read

    char* ws = (char*)d_ws;
    const size_t h0_b  = (size_t)256*512*128*2;
    const size_t h1_b  = (size_t)256*256*128*2;
    const size_t c0f_b = (size_t)256*512*128*4;
    const size_t c1f_b = (size_t)256*256*128*4;
    __bf16* h0 = (__bf16*)ws;
    __bf16* h1 = (__bf16*)(ws + h0_b);
    char* cb   = ws + h0_b + h1_b;
    const size_t lds = 131072;
    dim3 grid(256), blk(512);

    if (ws_size >= h0_b + h1_b + c0f_b + c1f_b){
        float* c0 = (float*)cb;
        float* c1 = (float*)(cb + c0f_b);
        hipFuncSetAttribute((const void*)&treelstm_kernel<float>,
                            hipFuncAttributeMaxDynamicSharedMemorySize, (int)lds);
        treelstm_kernel<float><<<grid, blk, lds, stream>>>(
            feats,W1,b1,Wiou,Uiou,biou,Uf,bf,Wout,bout,out,h0,h1,c0,c1,cred);
    } else {
        __bf16* c0 = (__bf16*)cb;
        __bf16* c1 = (__bf16*)(cb + c0f_b/2);
        hipFuncSetAttribute((const void*)&treelstm_kernel<__bf16>,
                            hipFuncAttributeMaxDynamicSharedMemorySize, (int)lds);
        treelstm_kernel<__bf16><<<grid, blk, lds, stream>>>(
            feats,W1,b1,Wiou,Uiou,biou,Uf,bf,Wout,bout,out,h0,h1,c0,c1,cred);
    }
}

// Round 2
// 365.894 us; speedup vs baseline: 2.0405x; 2.0405x over previous
//
#include <hip/hip_runtime.h>
#include <hip/hip_bf16.h>

// TreeLSTM, fully fused: one workgroup per tree (256 trees == 256 CUs), zero
// HBM traffic for intermediates. Waves are COLUMN-partitioned: wave w owns
// cols 16w..16w+15 of every GEMM output, so the cell state c stays in f32
// registers (MFMA D-fragment layout) through all 10 levels. h passes between
// levels via LDS only. Weights: Uf/Uiou/Wiou in per-wave register B-frags,
// W1 in LDS. Level 8 is fused into the leaf loop per 128-row chunk.

typedef __bf16 bf16x8 __attribute__((ext_vector_type(8)));
typedef float  f32x4  __attribute__((ext_vector_type(4)));

#define MFMA16(a,b,c) __builtin_amdgcn_mfma_f32_16x16x32_bf16((a),(b),(c),0,0,0)

__device__ __forceinline__ float fast_sigmoid(float x){
    return __builtin_amdgcn_rcpf(1.0f + __expf(-x));   // inf-safe
}
__device__ __forceinline__ float fast_tanh(float x){
    float ax = fabsf(x);
    float e  = __expf(-2.0f*ax);                        // (0,1]: no overflow
    float t  = (1.0f - e) * __builtin_amdgcn_rcpf(1.0f + e);
    return x < 0.0f ? -t : t;
}
__device__ __forceinline__ unsigned pack2bf(float a, float b){
    unsigned short ua = __builtin_bit_cast(unsigned short, (__bf16)a);
    unsigned short ub = __builtin_bit_cast(unsigned short, (__bf16)b);
    return (unsigned)ua | ((unsigned)ub << 16);
}
// swizzled byte offset in a [rows][128] bf16 LDS tile (row stride 256B)
__device__ __forceinline__ int swzoff(int row, int kByte){
    return row*256 + (kByte ^ ((row & 7) << 4));
}
// A/B fragment: row = rowBase+(lane&15), elems 32*ks+8*(lane>>4)..+7
__device__ __forceinline__ bf16x8 lds_frag(const char* base, int rowBase, int lane, int ks){
    int row = rowBase + (lane & 15);
    int kB  = ks*64 + ((lane >> 4) << 4);
    return *(const bf16x8*)(base + swzoff(row, kB));
}
// h_cat fragment: rows row0,row0+1 summed (fixed fan-in 2)
__device__ __forceinline__ bf16x8 lds_pair_frag(const char* base, int row0, int q, int ks){
    bf16x8 ha = *(const bf16x8*)(base + swzoff(row0,     ks*64 + q*16));
    bf16x8 hb = *(const bf16x8*)(base + swzoff(row0 + 1, ks*64 + q*16));
    bf16x8 t;
    #pragma unroll
    for (int e=0;e<8;++e) t[e] = (__bf16)((float)ha[e] + (float)hb[e]);
    return t;
}
// weight B-fragment from global f32: row fixed per lane, k = 32ks+8q..+7
__device__ __forceinline__ bf16x8 gfrag(const float* __restrict__ W, int row, int q, int ks){
    const float* p = W + row*128 + ks*32 + q*8;
    f32x4 lo = *(const f32x4*)p;
    f32x4 hi = *(const f32x4*)(p+4);
    bf16x8 t;
    t[0]=(__bf16)lo[0]; t[1]=(__bf16)lo[1]; t[2]=(__bf16)lo[2]; t[3]=(__bf16)lo[3];
    t[4]=(__bf16)hi[0]; t[5]=(__bf16)hi[1]; t[6]=(__bf16)hi[2]; t[7]=(__bf16)hi[3];
    return t;
}
// f32 [rows][128] global -> bf16 swizzled LDS
__device__ __forceinline__ void load_w_lds(char* dst, const float* __restrict__ src,
                                           int rows, int tid){
    int total = rows * 32;
    for (int t = tid; t < total; t += 512){
        int row = t >> 5;
        int kq  = (t & 31) << 2;
        f32x4 v = *(const f32x4*)(src + row*128 + kq);
        unsigned long long val = (unsigned long long)pack2bf(v[0], v[1])
                               | ((unsigned long long)pack2bf(v[2], v[3]) << 32);
        *(unsigned long long*)(dst + swzoff(row, kq*2)) = val;
    }
}

struct UFrags {
    bf16x8 uf[4], ui[4], uo[4], uu[4];
    float bi, bo, bu, bfc;
};

// One tree level with N nodes (children: 2N rows in childR, c in L(2N) layout).
// c layout L(n): c[t][m] in lane(q,r) of wave w <-> node 16t+4q+m, col 16w+r.
template<int N>
__device__ __forceinline__ void level_step(float (&c)[16][4], const char* childR, char* curR,
                                           const UFrags& W, int lane, int colb2){
    const int q = lane >> 4, r = lane & 15;
    constexpr int NCC = (2*N)/16 > 0 ? (2*N)/16 : 1;   // child row chunks
    constexpr int NC  = N/16 > 0 ? N/16 : 1;           // node row chunks
    constexpr int REDN = NCC > 2 ? NCC : 2;
    float red[REDN][2];
    #pragma unroll
    for (int t=NCC;t<REDN;++t){ red[t][0]=0.f; red[t][1]=0.f; }   // tail-safe
    // F step: fpre = h_child @ Uf^T; fc = sigmoid(fpre+bf)*c; pair-sum in-lane
    #pragma unroll
    for (int t=0;t<NCC;++t){
        f32x4 acc = {0.f,0.f,0.f,0.f};
        #pragma unroll
        for (int ks=0;ks<4;++ks)
            acc = MFMA16(lds_frag(childR, 16*t, lane, ks), W.uf[ks], acc);
        red[t][0] = fast_sigmoid(acc[0]+W.bfc)*c[t][0] + fast_sigmoid(acc[1]+W.bfc)*c[t][1];
        red[t][1] = fast_sigmoid(acc[2]+W.bfc)*c[t][2] + fast_sigmoid(acc[3]+W.bfc)*c[t][3];
    }
    // fold red (node nu = 8t+2q+j) into L(N): node 16tau+4q+m'
    #pragma unroll
    for (int tau=0; tau<NC; ++tau){
        #pragma unroll
        for (int mp=0; mp<4; ++mp){
            int s   = 4*q + mp;
            int src = ((s>>1)&3)*16 + r;
            float va = __shfl(red[2*tau  ][mp&1], src, 64);
            float vb = __shfl(red[2*tau+1][mp&1], src, 64);
            c[tau][mp] = (q >= 2) ? vb : va;
        }
    }
    // IOU step: iou = (h2j+h2j+1) @ Uiou^T; apply_node with c_red; h -> curR
    #pragma unroll
    for (int tau=0; tau<NC; ++tau){
        f32x4 ai={0.f,0.f,0.f,0.f}, ao=ai, au=ai;
        #pragma unroll
        for (int ks=0;ks<4;++ks){
            bf16x8 a = lds_pair_frag(childR, 32*tau + 2*r, q, ks);
            ai = MFMA16(a, W.ui[ks], ai);
            ao = MFMA16(a, W.uo[ks], ao);
            au = MFMA16(a, W.uu[ks], au);
        }
        #pragma unroll
        for (int m=0;m<4;++m){
            int row = 16*tau + 4*q + m;
            float cv = fast_sigmoid(ai[m]+W.bi)*fast_tanh(au[m]+W.bu) + c[tau][m];
            float hv = fast_sigmoid(ao[m]+W.bo)*fast_tanh(cv);
            c[tau][m] = cv;
            if (N >= 16 || (4*q + m) < N)
                *(__bf16*)(curR + swzoff(row, colb2)) = (__bf16)hv;
        }
    }
    __syncthreads();
}

__global__ __launch_bounds__(512, 2)
void treelstm_fused(const float* __restrict__ feats,
                    const float* __restrict__ W1,   const float* __restrict__ b1,
                    const float* __restrict__ Wiou, const float* __restrict__ Uiou,
                    const float* __restrict__ biou, const float* __restrict__ Uf,
                    const float* __restrict__ bfv,  const float* __restrict__ Wout,
                    const float* __restrict__ bout, float* __restrict__ out)
{
    extern __shared__ char smem[];
    char* stg1   = smem;            // 32 KB: x staging; later levels 7,5,3,1
    char* stg2   = smem + 32768;    // 32 KB: leaf-h chunk; later c_root buf
    char* arenaA = smem + 65536;    // 64 KB: level 8 h; later levels 6,4,2,0
    char* w1L    = smem + 131072;   // 32 KB: W1 bf16 (leaf phase only)

    const int tid  = threadIdx.x;
    const int lane = tid & 63;
    const int wave = tid >> 6;
    const int q    = lane >> 4;
    const int r    = lane & 15;
    const int colw = 16*wave + r;   // this wave's output column for lane r
    const int colb2= 2*colw;
    const int tree = blockIdx.x;

    load_w_lds(w1L, W1, 128, tid);

    UFrags W;
    bf16x8 wi[4], wo[4], wu[4];
    #pragma unroll
    for (int ks=0;ks<4;++ks){
        W.uf[ks] = gfrag(Uf,   colw,     q, ks);
        W.ui[ks] = gfrag(Uiou, colw,     q, ks);
        W.uo[ks] = gfrag(Uiou, 128+colw, q, ks);
        W.uu[ks] = gfrag(Uiou, 256+colw, q, ks);
        wi[ks]   = gfrag(Wiou, colw,     q, ks);
        wo[ks]   = gfrag(Wiou, 128+colw, q, ks);
        wu[ks]   = gfrag(Wiou, 256+colw, q, ks);
    }
    W.bi = biou[colw]; W.bo = biou[128+colw]; W.bu = biou[256+colw]; W.bfc = bfv[colw];
    const float b1c = b1[colw];

    __syncthreads();

    const float* featsT = feats + ((size_t)tree*1023 + 511)*128;   // leaf rows
    float c[16][4];   // cell state, L(n) layout, f32 end-to-end

    // ---- leaf phase + fused level 8: 4 chunks of 128 leaves / 64 nodes ----
    #pragma unroll
    for (int ci=0; ci<4; ++ci){
        // (a) x = relu(feats @ W1^T + b1) -> stg1
        #pragma unroll
        for (int t=0;t<8;++t){
            f32x4 acc = {0.f,0.f,0.f,0.f};
            #pragma unroll
            for (int ks=0;ks<4;++ks){
                const float* p = featsT + (size_t)(ci*128 + t*16 + r)*128 + ks*32 + q*8;
                f32x4 lo = *(const f32x4*)p;
                f32x4 hi = *(const f32x4*)(p+4);
                bf16x8 a;
                a[0]=(__bf16)lo[0]; a[1]=(__bf16)lo[1]; a[2]=(__bf16)lo[2]; a[3]=(__bf16)lo[3];
                a[4]=(__bf16)hi[0]; a[5]=(__bf16)hi[1]; a[6]=(__bf16)hi[2]; a[7]=(__bf16)hi[3];
                acc = MFMA16(a, lds_frag(w1L, 16*wave, lane, ks), acc);
            }
            #pragma unroll
            for (int m=0;m<4;++m){
                float xv = fmaxf(acc[m] + b1c, 0.f);
                *(__bf16*)(stg1 + swzoff(16*t + 4*q + m, colb2)) = (__bf16)xv;
            }
        }
        __syncthreads();
        // (b) iou = x @ Wiou^T; apply_node(c_in=0): h -> stg2, c -> regs
        float c0c[8][4];
        #pragma unroll
        for (int t=0;t<8;++t){
            f32x4 ai={0.f,0.f,0.f,0.f}, ao=ai, au=ai;
            #pragma unroll
            for (int ks=0;ks<4;++ks){
                bf16x8 a = lds_frag(stg1, 16*t, lane, ks);
                ai = MFMA16(a, wi[ks], ai);
                ao = MFMA16(a, wo[ks], ao);
                au = MFMA16(a, wu[ks], au);
            }
            #pragma unroll
            for (int m=0;m<4;++m){
                float cv = fast_sigmoid(ai[m]+W.bi)*fast_tanh(au[m]+W.bu);
                float hv = fast_sigmoid(ao[m]+W.bo)*fast_tanh(cv);
                c0c[t][m] = cv;
                *(__bf16*)(stg2 + swzoff(16*t + 4*q + m, colb2)) = (__bf16)hv;
            }
        }
        __syncthreads();
        // (c) leaf F-gates + pair-reduce + fold -> c chunks 4ci..4ci+3
        float red[8][2];
        #pragma unroll
        for (int t=0;t<8;++t){
            f32x4 acc = {0.f,0.f,0.f,0.f};
            #pragma unroll
            for (int ks=0;ks<4;++ks)
                acc = MFMA16(lds_frag(stg2, 16*t, lane, ks), W.uf[ks], acc);
            red[t][0] = fast_sigmoid(acc[0]+W.bfc)*c0c[t][0] + fast_sigmoid(acc[1]+W.bfc)*c0c[t][1];
            red[t][1] = fast_sigmoid(acc[2]+W.bfc)*c0c[t][2] + fast_sigmoid(acc[3]+W.bfc)*c0c[t][3];
        }
        #pragma unroll
        for (int tau=0;tau<4;++tau){
            #pragma unroll
            for (int mp=0;mp<4;++mp){
                int s   = 4*q + mp;
                int src = ((s>>1)&3)*16 + r;
                float va = __shfl(red[2*tau  ][mp&1], src, 64);
                float vb = __shfl(red[2*tau+1][mp&1], src, 64);
                c[4*ci+tau][mp] = (q >= 2) ? vb : va;
            }
        }
        // (d) level-8 IOU for nodes 64ci..64ci+63: h8 -> arenaA
        #pragma unroll
        for (int tau=0;tau<4;++tau){
            f32x4 ai={0.f,0.f,0.f,0.f}, ao=ai, au=ai;
            #pragma unroll
            for (int ks=0;ks<4;++ks){
                bf16x8 a = lds_pair_frag(stg2, 32*tau + 2*r, q, ks);
                ai = MFMA16(a, W.ui[ks], ai);
                ao = MFMA16(a, W.uo[ks], ao);
                au = MFMA16(a, W.uu[ks], au);
            }
            #pragma unroll
            for (int m=0;m<4;++m){
                float cv = fast_sigmoid(ai[m]+W.bi)*fast_tanh(au[m]+W.bu) + c[4*ci+tau][m];
                float hv = fast_sigmoid(ao[m]+W.bo)*fast_tanh(cv);
                c[4*ci+tau][m] = cv;
                *(__bf16*)(arenaA + swzoff(64*ci + 16*tau + 4*q + m, colb2)) = (__bf16)hv;
            }
        }
        __syncthreads();
    }

    // ---- levels 7..0, h ping-pongs arenaA <-> stg1, c stays in regs ----
    level_step<128>(c, arenaA, stg1,   W, lane, colb2);
    level_step< 64>(c, stg1,   arenaA, W, lane, colb2);
    level_step< 32>(c, arenaA, stg1,   W, lane, colb2);
    level_step< 16>(c, stg1,   arenaA, W, lane, colb2);
    level_step<  8>(c, arenaA, stg1,   W, lane, colb2);
    level_step<  4>(c, stg1,   arenaA, W, lane, colb2);
    level_step<  2>(c, arenaA, stg1,   W, lane, colb2);
    level_step<  1>(c, stg1,   arenaA, W, lane, colb2);

    // ---- out = c_root @ Wout^T + bout ----
    float* cbuf = (float*)stg2;
    if (q == 0) cbuf[colw] = c[0][0];          // root row 0 lives in q==0, m==0
    __syncthreads();
    if (tid < 32){
        float acc = bout[tid];
        const float* wr = Wout + tid*128;
        #pragma unroll
        for (int k=0;k<128;k+=4){
            f32x4 wv = *(const f32x4*)(wr + k);
            acc += wv[0]*cbuf[k] + wv[1]*cbuf[k+1] + wv[2]*cbuf[k+2] + wv[3]*cbuf[k+3];
        }
        out[tree*32 + tid] = acc;
    }
}

extern "C" void kernel_launch(void* const* d_in, const int* in_sizes, int n_in,
                              void* d_out, int out_size, void* d_ws, size_t ws_size,
                              hipStream_t stream)
{
    (void)in_sizes; (void)n_in; (void)out_size; (void)d_ws; (void)ws_size;
    const float* feats = (const float*)d_in[0];
    const float* W1    = (const float*)d_in[2];
    const float* b1    = (const float*)d_in[3];
    const float* Wiou  = (const float*)d_in[4];
    const float* Uiou  = (const float*)d_in[5];
    const float* biou  = (const float*)d_in[6];
    const float* Uf    = (const float*)d_in[7];
    const float* bf    = (const float*)d_in[8];
    const float* Wout  = (const float*)d_in[9];
    const float* bout  = (const float*)d_in[10];
    float* out = (float*)d_out;

    const int lds = 163840;   // full 160 KB (AITER precedent on gfx950)
    hipFuncSetAttribute((const void*)&treelstm_fused,
                        hipFuncAttributeMaxDynamicSharedMemorySize, lds);
    treelstm_fused<<<dim3(256), dim3(512), lds, stream>>>(
        feats, W1, b1, Wiou, Uiou, biou, Uf, bf, Wout, bout, out);
}